// Round 9
// baseline (123.235 us; speedup 1.0000x reference)
//
#include <hip/hip_runtime.h>

typedef unsigned short u16;
typedef unsigned int u32;
typedef __attribute__((ext_vector_type(8))) short short8;   // 8 bf16 (4 VGPRs)
typedef __attribute__((ext_vector_type(4))) float f32x4;

// ws layout (bytes), all 16B-aligned
#define WS_W3T  0        // float[96]  (W3 augmented: [90]=b3, [91..95]=0)
#define WS_W0F  384      // u16[6][6*64*8]  per-o L1 fragments w/ bias rows k=5..9
#define WS_W1F  37248    // u16[18*64*8]
#define WS_W2F  55680    // u16[18*64*8]   (ends 74112)

__device__ __forceinline__ u16 f2b(float f) {  // RNE f32 -> bf16 (prep only)
  union { float f; u32 i; } v; v.f = f;
  u32 i = v.i;
  return (u16)((i + 0x7FFFu + ((i >> 16) & 1u)) >> 16);
}

// 3-op bf16 pair pack (round-half-up + v_perm). Verified R7: -18k VALU cyc/SIMD.
__device__ __forceinline__ u32 pk2(float a, float b) {  // a -> low half, b -> high
  u32 ia = __float_as_uint(a) + 0x8000u;
  u32 ib = __float_as_uint(b) + 0x8000u;
  return __builtin_amdgcn_perm(ib, ia, 0x07060302u);
}

// Compiler-only memory barrier: stops LICM from hoisting the per-iteration
// LDS weight streams back into (nonexistent) registers.
__device__ __forceinline__ void lds_compiler_fence() {
  asm volatile("" ::: "memory");
}

// prep: identical to R8 (verified absmax 7.8e-3).
__global__ void prep_kernel(const float* __restrict__ ac, const float* __restrict__ W0,
                            const float* __restrict__ b0, const float* __restrict__ W1,
                            const float* __restrict__ b1, const float* __restrict__ W2,
                            const float* __restrict__ b2, const float* __restrict__ W3,
                            const float* __restrict__ b3,
                            float* __restrict__ w3t, u16* __restrict__ W0f,
                            u16* __restrict__ W1f, u16* __restrict__ W2f) {
  int tid = blockIdx.x * blockDim.x + threadIdx.x;
  int nth = gridDim.x * blockDim.x;
  for (int i = tid; i < 96; i += nth)
    w3t[i] = (i < 90) ? W3[i] : ((i == 90) ? b3[0] : 0.0f);
  // W0f[o][t][lane][jj]: A[m=unit][k]; k<5: taps (W0 rows {5,0,1,2,3});
  // k=5+dd: bias row for device dd of channel o; (k=5+dd, u=90) = 1.0.
  for (int i = tid; i < 6 * 6 * 64 * 8; i += nth) {
    int o = i / 3072, rem = i % 3072;
    int t = rem >> 9, lane = (rem >> 3) & 63, jj = rem & 7;
    int q = lane >> 4, m = lane & 15;
    int k = q * 8 + jj;
    int u = t * 16 + m;
    u16 v = 0;
    if (k < 5) {
      const int rowmap[5] = {5, 0, 1, 2, 3};
      if (u < 90) v = f2b(W0[rowmap[k] * 90 + u]);
    } else if (k < 10) {
      int dd = k - 5;
      if (u < 90) {
        float c0 = ac[(o * 5 + dd) * 2 + 0], c1 = ac[(o * 5 + dd) * 2 + 1];
        v = f2b(b0[u] + c0 * W0[4 * 90 + u] + c1 * W0[6 * 90 + u]);
      } else if (u == 90) {
        v = (u16)0x3F80;  // the "1" unit
      }
    }
    W0f[i] = v;
  }
  // W1f/W2f: A-operands with PERMUTED K so D-layout feeds B directly.
  for (int i = tid; i < 2 * 18 * 64 * 8; i += nth) {
    int which = i / (18 * 64 * 8);
    int j2 = i % (18 * 64 * 8);
    int jj = j2 & 7, lane = (j2 >> 3) & 63, f = j2 >> 9;
    int t = f / 3, ki = f % 3;
    int qA = lane >> 4, m = lane & 15;
    int row = 32 * ki + 16 * (jj >> 2) + 4 * qA + (jj & 3);
    int col = 16 * t + m;
    const float* W = which ? W2 : W1;
    const float* bb = which ? b2 : b1;
    u16 v = 0;
    if (row < 90 && col < 90) v = f2b(W[row * 90 + col]);
    else if (row == 90) v = (col < 90) ? f2b(bb[col]) : ((col == 90) ? (u16)0x3F80 : (u16)0);
    (which ? W2f : W1f)[j2] = v;
  }
}

__device__ __forceinline__ f32x4 mfma16(short8 a, short8 b, f32x4 c) {
  return __builtin_amdgcn_mfma_f32_16x16x32_bf16(a, b, c, 0, 0, 0);
}

__device__ __forceinline__ short8 packB(const f32x4& a0, const f32x4& a1) {
  union { u32 u[4]; short8 s; } fu;
  fu.u[0] = pk2(fmaxf(a0.x, 0.f), fmaxf(a0.y, 0.f));
  fu.u[1] = pk2(fmaxf(a0.z, 0.f), fmaxf(a0.w, 0.f));
  fu.u[2] = pk2(fmaxf(a1.x, 0.f), fmaxf(a1.y, 0.f));
  fu.u[3] = pk2(fmaxf(a1.z, 0.f), fmaxf(a1.w, 0.f));
  return fu.s;
}

// One wave = TWO 16-sample tiles {w, w+5400}, 10 flattened (tile,d) iters.
// R9 change: w2f + w3 are STREAMED FROM LDS (one block-shared copy) instead
// of being register-resident. Cuts ~96 regs/wave (~250 -> ~160), unlocking
// 3 waves/SIMD under __launch_bounds__(256,3) (cap 512/3 = 170 regs) —
// R8's counters showed the 2-wave phase-locked stall (28% idle) was the
// limiter, caused purely by register footprint.
__global__ __launch_bounds__(256, 3) void mlp_kernel(
    const float* __restrict__ x, const float* __restrict__ w3t,
    const u16* __restrict__ W0f, const u16* __restrict__ W1f,
    const u16* __restrict__ W2f, float* __restrict__ out) {
  __shared__ short8 ldsW2[18 * 64];  // 18432 B, frag order == global layout
  __shared__ float ldsW3[96];        // 384 B
  const int tid = threadIdx.x;
  {  // cooperative one-time fill (amortized over all 4 waves x 2 tiles)
    const uint4* src = (const uint4*)W2f;
    uint4* dst = (uint4*)ldsW2;
#pragma unroll
    for (int i = 0; i < 5; ++i) {  // 5*256 >= 1152
      int j = tid + i * 256;
      if (j < 1152) dst[j] = src[j];
    }
    if (tid < 96) ldsW3[tid] = w3t[tid];
  }
  __syncthreads();

  const int lane = tid & 63;
  const int wv = tid >> 6;
  const int q = lane >> 4, n = lane & 15;
  const int w = blockIdx.x * 4 + wv;  // 0..5399; tiles {w, w+5400}

  const int seg0 = w / 225;            // b*6+o   (tile1: seg0+24, same o)
  const int l0 = (w % 225) * 16;
  const int bb0 = seg0 / 6, o = seg0 % 6;

  // resident weights: w0f (24) + w1f (72) only
  short8 w0f[6], w1f[6][3];
  const short8* p0 = (const short8*)W0f + o * 384;
  const short8* p1 = (const short8*)W1f;
#pragma unroll
  for (int t = 0; t < 6; ++t) w0f[t] = p0[t * 64 + lane];
#pragma unroll
  for (int t = 0; t < 6; ++t)
#pragma unroll
    for (int ki = 0; ki < 3; ++ki) w1f[t][ki] = p1[(t * 3 + ki) * 64 + lane];

  const int l = l0 + n;
  const int oh = l / 60, ow = l - oh * 60;
  const float* xrow0 = x + (bb0 * 4096 + oh * 64 + ow);
  const float* xrow1 = xrow0 + 4 * 4096;  // batch +4

  const f32x4 z4 = {0.f, 0.f, 0.f, 0.f};
  float outAcc0 = 0.f, outAcc1 = 0.f;

  // prefetch taps for j=0
  float pa0 = xrow0[0], pa1 = xrow0[1], pa2 = xrow0[2], pa3 = xrow0[3], pa4 = xrow0[4];

#pragma unroll 1
  for (int j = 0; j < 10; ++j) {
    float c0 = pa0, c1 = pa1, c2 = pa2, c3 = pa3, c4 = pa4;
    int jn = j + 1;
    if (jn < 10) {
      const float* xp = (jn < 5) ? (xrow0 + jn * 64) : (xrow1 + (jn - 5) * 64);
      pa0 = xp[0]; pa1 = xp[1]; pa2 = xp[2]; pa3 = xp[3]; pa4 = xp[4];
    }
    const int d = (j < 5) ? j : j - 5;

    // one-hot(d) bias-selector slots k=5..9 (wave-uniform -> SALU)
    const u32 u3c = (d == 1) ? 0x00003F80u : ((d == 2) ? 0x3F800000u : 0u);  // k6,k7
    const u32 q1c = (d == 3) ? 0x00003F80u : ((d == 4) ? 0x3F800000u : 0u);  // k8,k9
    const float k5f = (d == 0) ? 1.0f : 0.0f;                                // k5

    union { u32 u[4]; short8 s; } bu;
    u32 t01 = pk2(c0, c1);
    bu.u[0] = (q == 1) ? q1c : t01;
    bu.u[1] = pk2(c2, c3);
    bu.u[2] = pk2(c4, k5f);
    bu.u[3] = u3c;
    short8 bx = bu.s;

    // ---- L1 (C = 0; bias rides W0f rows 5..9 via the one-hot)
    f32x4 acc[6];
#pragma unroll
    for (int t = 0; t < 6; ++t) acc[t] = mfma16(w0f[t], bx, z4);

    short8 h[3];
#pragma unroll
    for (int ki = 0; ki < 3; ++ki) h[ki] = packB(acc[2 * ki], acc[2 * ki + 1]);

    // ---- L2 (resident w1f)
#pragma unroll
    for (int t = 0; t < 6; ++t) {
      f32x4 a = z4;
#pragma unroll
      for (int ki = 0; ki < 3; ++ki) a = mfma16(w1f[t][ki], h[ki], a);
      acc[t] = a;
    }
#pragma unroll
    for (int ki = 0; ki < 3; ++ki) h[ki] = packB(acc[2 * ki], acc[2 * ki + 1]);

    // ---- L3 streamed from LDS + L4 dot (w3 streamed). unroll 1 caps the
    // number of simultaneously-live streamed fragments (register budget).
    lds_compiler_fence();  // force per-iteration ds_reads (no LICM re-hoist)
    float r = 0.f;
#pragma unroll 1
    for (int t = 0; t < 6; ++t) {
      f32x4 a = z4;
#pragma unroll
      for (int ki = 0; ki < 3; ++ki)
        a = mfma16(ldsW2[(t * 3 + ki) * 64 + lane], h[ki], a);
      f32x4 w3v = *(const f32x4*)&ldsW3[t * 16 + q * 4];
      r += fmaxf(a.x, 0.f) * w3v.x + fmaxf(a.y, 0.f) * w3v.y +
           fmaxf(a.z, 0.f) * w3v.z + fmaxf(a.w, 0.f) * w3v.w;
    }
    if (j < 5) outAcc0 += r; else outAcc1 += r;
  }

  // reduce quad-partials and store both tiles
  outAcc0 += __shfl_xor(outAcc0, 16, 64);
  outAcc0 += __shfl_xor(outAcc0, 32, 64);
  outAcc1 += __shfl_xor(outAcc1, 16, 64);
  outAcc1 += __shfl_xor(outAcc1, 32, 64);
  if (lane < 16) {
    out[seg0 * 3600 + l0 + lane] = outAcc0;
    out[(seg0 + 24) * 3600 + l0 + lane] = outAcc1;
  }
}

extern "C" void kernel_launch(void* const* d_in, const int* in_sizes, int n_in,
                              void* d_out, int out_size, void* d_ws, size_t ws_size,
                              hipStream_t stream) {
  const float* x  = (const float*)d_in[0];
  const float* ac = (const float*)d_in[1];
  const float* W0 = (const float*)d_in[2];
  const float* b0 = (const float*)d_in[3];
  const float* W1 = (const float*)d_in[4];
  const float* b1 = (const float*)d_in[5];
  const float* W2 = (const float*)d_in[6];
  const float* b2 = (const float*)d_in[7];
  const float* W3 = (const float*)d_in[8];
  const float* b3 = (const float*)d_in[9];
  float* out = (float*)d_out;
  char* ws = (char*)d_ws;
  float* w3t = (float*)(ws + WS_W3T);
  u16* W0f = (u16*)(ws + WS_W0F);
  u16* W1f = (u16*)(ws + WS_W1F);
  u16* W2f = (u16*)(ws + WS_W2F);
  prep_kernel<<<128, 256, 0, stream>>>(ac, W0, b0, W1, b1, W2, b2, W3, b3,
                                       w3t, W0f, W1f, W2f);
  mlp_kernel<<<1350, 256, 0, stream>>>(x, w3t, W0f, W1f, W2f, out);
}